// Round 5
// baseline (352.781 us; speedup 1.0000x reference)
//
#include <hip/hip_runtime.h>
#include <math.h>

typedef _Float16 half4_t __attribute__((ext_vector_type(4)));
typedef __fp16   fp16x2  __attribute__((ext_vector_type(2)));
typedef float    f32x4   __attribute__((ext_vector_type(4)));

#define B_   32
#define NQ_  16384
#define NK_  31
#define DM_  64
#define PITCH 132   // f16 units; 132*2B = 264B row pitch -> b64 reads spread 4/bank (minimum)

static __device__ __forceinline__ half4_t cvt4(f32x4 f) {
  fp16x2 lo = __builtin_amdgcn_cvt_pkrtz(f[0], f[1]);
  fp16x2 hi = __builtin_amdgcn_cvt_pkrtz(f[2], f[3]);
  half4_t r;
  r[0] = (_Float16)lo[0]; r[1] = (_Float16)lo[1];
  r[2] = (_Float16)hi[0]; r[3] = (_Float16)hi[1];
  return r;
}

// ---------------------------------------------------------------------------
// Single fused kernel, register-slimmed for occupancy.
// Per block (4 waves): wave w computes VW d-rows [16w,16w+16) via 8 prologue
// MFMAs (V_h x W_h^T) and parks them in LDS (pitch 132 f16 -> conflict-min
// b64 A-frag reads). Main loop: 4 tiles of 16 queries per wave, Q prefetched
// one iter ahead; GEMM1 (mask folded into C operand) -> exp/normalize ->
// GEMM2 (A from LDS) -> +bias -> nontemporal dwordx4 store.
// __launch_bounds__(256,4): cap combined VGPR+AGPR at 128 -> 4 waves/SIMD.
// ---------------------------------------------------------------------------
__global__ __launch_bounds__(256, 4) void attn(
    const float* __restrict__ Q, const float* __restrict__ K,
    const float* __restrict__ V, const unsigned char* __restrict__ mraw,
    const float* __restrict__ W, const float* __restrict__ bout,
    float* __restrict__ out) {
  __shared__ _Float16 vw[64 * PITCH];     // 16896 B

  int b    = blockIdx.x >> 6;             // 64 blocks per batch
  int blk  = blockIdx.x & 63;
  int tid  = threadIdx.x;
  int wave = tid >> 6, lane = tid & 63;
  int lq = lane & 15, quad = lane >> 4;

  // ---- mask word (per-wave ballot; dtype sniffed from raw bytes) ----
  unsigned mb;
  {
    unsigned char c0 = 0, c1 = 0;
    if (lane < 62) { c0 = mraw[2 * lane]; c1 = mraw[2 * lane + 1]; }
    unsigned long long m3f =
        __ballot(lane < 62 && (c0 == 0x3f || c1 == 0x3f));
    unsigned long long moff =
        __ballot(lane < 62 && ((((2 * lane) & 3) != 0 && c0 != 0) || c1 != 0));
    int mode = m3f ? 2 : (moff ? 0 : 1);
    int nz = 0;
    if (lane < NK_) {
      int idx = b * NK_ + lane;
      nz = (mode == 0) ? (mraw[idx] != 0)
         : (mode == 1) ? (((const int*)mraw)[idx] != 0)
                       : (((const float*)mraw)[idx] != 0.0f);
    }
    mb = (unsigned)__ballot(nz) & 0x7fffffffu;
  }

  // ---- mask bias for GEMM1's C operand (key 31 pad auto-masked) ----
  f32x4 cbias[2];
  #pragma unroll
  for (int tt = 0; tt < 2; ++tt)
    #pragma unroll
    for (int r = 0; r < 4; ++r) {
      int key = 16 * tt + 4 * quad + r;
      cbias[tt][r] = ((mb >> key) & 1u) ? 0.0f : -1e30f;
    }

  const f32x4 fzero = {0.f, 0.f, 0.f, 0.f};

  // ---- K fragments (A of GEMM1), scale 0.25 folded ----
  half4_t kf[2][4];
  #pragma unroll
  for (int tt = 0; tt < 2; ++tt) {
    int k = 16 * tt + lq;
    #pragma unroll
    for (int h = 0; h < 4; ++h) {
      f32x4 f = fzero;
      if (k < NK_)
        f = *(const f32x4*)(K + ((size_t)b * NK_ + k) * DM_ + 16 * h + 4 * quad);
      kf[tt][h] = cvt4(f * 0.25f);
    }
  }

  // ---- prologue: this wave computes VW d-rows [16*wave, 16*wave+16) ----
  {
    int dt = wave;
    half4_t bf[4];
    #pragma unroll
    for (int h = 0; h < 4; ++h) {
      f32x4 f = *(const f32x4*)(W + (16 * dt + lq) * DM_ + 16 * h + 4 * quad);
      bf[h] = cvt4(f);
    }
    #pragma unroll
    for (int s = 0; s < 8; ++s) {
      int k = 16 * (s & 1) + lq, h = s >> 1;
      f32x4 f = fzero;
      if (k < NK_)
        f = *(const f32x4*)(V + ((size_t)b * NK_ + k) * DM_ + 16 * h + 4 * quad);
      f32x4 m = __builtin_amdgcn_mfma_f32_16x16x16f16(cvt4(f), bf[h], fzero, 0, 0, 0);
      *(half4_t*)&vw[(16 * dt + lq) * PITCH + 16 * s + 4 * quad] = cvt4(m);
    }
  }

  // ---- bias fragments for the epilogue ----
  f32x4 bias[4];
  #pragma unroll
  for (int dt = 0; dt < 4; ++dt)
    bias[dt] = *(const f32x4*)(bout + 16 * dt + 4 * quad);

  __syncthreads();

  // ---- main loop: 4 tiles of 16 queries ----
  int w = blk * 4 + wave;                 // 0..255 within batch
  const float* qrow = Q + ((size_t)b * NQ_ + lq) * DM_ + 4 * quad;

  f32x4 qraw[4];
  #pragma unroll
  for (int h = 0; h < 4; ++h)
    qraw[h] = *(const f32x4*)(qrow + (size_t)(w * 16) * DM_ + 16 * h);

  #pragma unroll 1
  for (int it = 0; it < 4; ++it) {
    int q0 = (w + it * 256) * 16;

    f32x4 qnext[4];
    if (it < 3) {
      #pragma unroll
      for (int h = 0; h < 4; ++h)
        qnext[h] = *(const f32x4*)(qrow + (size_t)(q0 + 4096) * DM_ + 16 * h);
    }

    half4_t qf[4];
    #pragma unroll
    for (int h = 0; h < 4; ++h) qf[h] = cvt4(qraw[h]);

    // GEMM1 + softmax (per head)
    half4_t pf[8];
    #pragma unroll
    for (int h = 0; h < 4; ++h) {
      f32x4 c0 = __builtin_amdgcn_mfma_f32_16x16x16f16(kf[0][h], qf[h], cbias[0], 0, 0, 0);
      f32x4 c1 = __builtin_amdgcn_mfma_f32_16x16x16f16(kf[1][h], qf[h], cbias[1], 0, 0, 0);
      f32x4 e0, e1;
      #pragma unroll
      for (int r = 0; r < 4; ++r) { e0[r] = __expf(c0[r]); e1[r] = __expf(c1[r]); }
      float sum = (e0[0] + e0[1]) + (e0[2] + e0[3]) +
                  (e1[0] + e1[1]) + (e1[2] + e1[3]);
      sum += __shfl_xor(sum, 16);
      sum += __shfl_xor(sum, 32);
      float inv = (sum > 0.f) ? __builtin_amdgcn_rcpf(sum) : 0.f;
      pf[2 * h + 0] = cvt4(e0 * inv);
      pf[2 * h + 1] = cvt4(e1 * inv);
    }

    // GEMM2: A fragments streamed from LDS (b64, conflict-minimal)
    f32x4 acc[4] = {fzero, fzero, fzero, fzero};
    #pragma unroll
    for (int s = 0; s < 8; ++s)
      #pragma unroll
      for (int dt = 0; dt < 4; ++dt) {
        half4_t a = *(const half4_t*)&vw[(16 * dt + lq) * PITCH + 16 * s + 4 * quad];
        acc[dt] = __builtin_amdgcn_mfma_f32_16x16x16f16(a, pf[s], acc[dt], 0, 0, 0);
      }

    // epilogue: +bias, nontemporal dwordx4 store (out has zero reuse)
    float* obase = out + ((size_t)b * NQ_ + q0 + lq) * DM_ + 4 * quad;
    #pragma unroll
    for (int dt = 0; dt < 4; ++dt) {
      f32x4 r = acc[dt] + bias[dt];
      __builtin_nontemporal_store(r, (f32x4*)(obase + 16 * dt));
    }

    if (it < 3) {
      #pragma unroll
      for (int h = 0; h < 4; ++h) qraw[h] = qnext[h];
    }
  }
}

extern "C" void kernel_launch(void* const* d_in, const int* in_sizes, int n_in,
                              void* d_out, int out_size, void* d_ws, size_t ws_size,
                              hipStream_t stream) {
  const float*         Q    = (const float*)d_in[0];
  const float*         K    = (const float*)d_in[1];
  const float*         V    = (const float*)d_in[2];
  const unsigned char* mask = (const unsigned char*)d_in[3];
  const float*         W    = (const float*)d_in[4];
  const float*         bo   = (const float*)d_in[5];
  float*               out  = (float*)d_out;

  hipLaunchKernelGGL(attn, dim3(B_ * 64), dim3(256), 0, stream,
                     Q, K, V, mask, W, bo, out);
}